// Round 3
// baseline (217.132 us; speedup 1.0000x reference)
//
#include <hip/hip_runtime.h>

#define T_TOK 2048
#define D_DIM 512
#define F_DIM 2048
#define E_NUM 8
#define LN_EPS 1e-5f

typedef __attribute__((ext_vector_type(8))) short bf16x8;
typedef __attribute__((ext_vector_type(4))) float floatx4;

static __device__ __forceinline__ float bf2f(ushort h) {
  union { unsigned int u; float f; } v; v.u = ((unsigned int)h) << 16; return v.f;
}
static __device__ __forceinline__ ushort f2bf(float f) {
  union { float f; unsigned int u; } v; v.f = f;
  unsigned int u = v.u;
  return (ushort)((u + 0x7fffu + ((u >> 16) & 1u)) >> 16);  // RNE
}

// ---------------- router: per-token expert argmax + alpha + LN stats (f32 in) ----------------
__global__ __launch_bounds__(256) void router_kernel(
    const float* __restrict__ x, const float* __restrict__ cent,
    int* __restrict__ eid, float* __restrict__ alphav,
    float* __restrict__ muv, float* __restrict__ rsigv) {
  int wave = threadIdx.x >> 6, lane = threadIdx.x & 63;
  int t = blockIdx.x * 4 + wave;
  const float* xp = x + (size_t)t * D_DIM + lane * 8;
  float4 x0 = *(const float4*)xp, x1 = *(const float4*)(xp + 4);
  float xv[8] = {x0.x, x0.y, x0.z, x0.w, x1.x, x1.y, x1.z, x1.w};
  float s = 0.f, s2 = 0.f, cd[E_NUM];
#pragma unroll
  for (int j = 0; j < 8; j++) { s += xv[j]; s2 += xv[j] * xv[j]; }
#pragma unroll
  for (int e = 0; e < E_NUM; e++) {
    const float* cp = cent + (size_t)e * D_DIM + lane * 8;
    float4 c0 = *(const float4*)cp, c1 = *(const float4*)(cp + 4);
    float cv[8] = {c0.x, c0.y, c0.z, c0.w, c1.x, c1.y, c1.z, c1.w};
    float a = 0.f;
#pragma unroll
    for (int j = 0; j < 8; j++) a += xv[j] * cv[j];
    cd[e] = a;
  }
#pragma unroll
  for (int m = 1; m < 64; m <<= 1) {
    s  += __shfl_xor(s,  m, 64);
    s2 += __shfl_xor(s2, m, 64);
#pragma unroll
    for (int e = 0; e < E_NUM; e++) cd[e] += __shfl_xor(cd[e], m, 64);
  }
  if (lane == 0) {
    float mu = s / (float)D_DIM;
    float var = s2 / (float)D_DIM - mu * mu;
    if (var < 0.f) var = 0.f;
    int best = 0;
#pragma unroll
    for (int e = 1; e < E_NUM; e++) if (cd[e] > cd[best]) best = e;  // first-max, like np.argmax
    eid[t] = best;
    alphav[t] = 1.f / (1.f + expf(-cd[best]));
    muv[t] = mu;
    rsigv[t] = rsqrtf(var + LN_EPS);
  }
}

// ---------------- build permutation (group tokens by expert) ----------------
__global__ __launch_bounds__(1024) void perm_kernel(
    const int* __restrict__ eid, int* __restrict__ perm, int* __restrict__ posof,
    int* __restrict__ cnt_g, int* __restrict__ offs_g) {
  __shared__ int cnt[E_NUM], offs[E_NUM], cur[E_NUM];
  if (threadIdx.x < E_NUM) cnt[threadIdx.x] = 0;
  __syncthreads();
  for (int t = threadIdx.x; t < T_TOK; t += 1024) atomicAdd(&cnt[eid[t]], 1);
  __syncthreads();
  if (threadIdx.x == 0) {
    int a = 0;
    for (int e = 0; e < E_NUM; e++) { offs[e] = a; cur[e] = a; a += cnt[e]; }
  }
  __syncthreads();
  for (int t = threadIdx.x; t < T_TOK; t += 1024) {
    int e = eid[t];
    int p = atomicAdd(&cur[e], 1);
    perm[p] = t;
    posof[t] = p;
  }
  if (threadIdx.x < E_NUM) { cnt_g[threadIdx.x] = cnt[threadIdx.x]; offs_g[threadIdx.x] = offs[threadIdx.x]; }
}

// ---------------- apply LN (f32 in) -> bf16 h0, written to permuted row ----------------
__global__ __launch_bounds__(64) void ln_apply_kernel(
    const float* __restrict__ x, const float* __restrict__ g, const float* __restrict__ b,
    const int* __restrict__ eid, const float* __restrict__ muv, const float* __restrict__ rsigv,
    const int* __restrict__ posof, ushort* __restrict__ h0p) {
  int t = blockIdx.x, lane = threadIdx.x;
  int e = eid[t];
  float mu = muv[t], rs = rsigv[t];
  int pos = posof[t];
  int c0 = lane * 8;
  const float* xp = x + (size_t)t * D_DIM + c0;
  const float* gp = g + (size_t)e * D_DIM + c0;
  const float* bp = b + (size_t)e * D_DIM + c0;
  union { ushort u16[8]; uint4 v; } o;
#pragma unroll
  for (int j = 0; j < 8; j++)
    o.u16[j] = f2bf((xp[j] - mu) * rs * gp[j] + bp[j]);
  *(uint4*)(h0p + (size_t)pos * D_DIM + c0) = o.v;
}

// ---------------- grouped GEMM, MFMA 16x16x32 bf16, 32x64 tile, BK=64 ----------------
// A: [T][KTOT] bf16 rows grouped by expert. W: [E][KTOT][NTOT] f32 natural layout,
// converted bf16 + transposed in LDS during staging -> Bs[kblk][n][8].
// MODE 1: H = relu(A*W + bias) (bf16, permuted rows)
// MODE 2: out[perm[row]] = x[perm[row]] + alpha*(A*W + bias)  (f32)
template<int KTOT, int NTOT, int MODE>
__global__ __launch_bounds__(256) void moe_gemm_kernel(
    const ushort* __restrict__ A, const float* __restrict__ W,
    const float* __restrict__ bias,
    const int* __restrict__ cnt, const int* __restrict__ offs,
    const int* __restrict__ perm, const float* __restrict__ alphav,
    const float* __restrict__ xin, ushort* __restrict__ CoutH, float* __restrict__ CoutF) {
  constexpr int BK = 64;
  constexpr int LDA = BK + 8;  // pad: frag reads 2-way bank aliasing (free, m136)
  int e = blockIdx.z, mt = blockIdx.y, nt = blockIdx.x;
  int ce = cnt[e];
  if (mt * 32 >= ce) return;  // uniform early-exit before any barrier
  int rowbase = offs[e] + mt * 32;
  int n0 = nt * 64;

  __shared__ ushort As[32 * LDA];    // [m][k] row-major, padded
  __shared__ ushort Bs[8 * 64 * 8];  // [kblk][n][k_in_blk]; frag reads contiguous 16B

  int tid = threadIdx.x;
  int lane = tid & 63, wave = tid >> 6;
  int mw = (wave >> 1) * 16, nw = (wave & 1) * 32;  // wave's 16x32 sub-tile
  int fm = lane & 15, quad = lane >> 4;

  floatx4 acc0 = {0.f, 0.f, 0.f, 0.f}, acc1 = {0.f, 0.f, 0.f, 0.f};

  // A staging: 32 rows x 64 cols bf16, uint4 per thread
  int a_row = tid >> 3, a_col = (tid & 7) * 8;
  int ga_row = rowbase + a_row;
  if (ga_row > T_TOK - 1) ga_row = T_TOK - 1;  // clamp; masked rows never stored
  const ushort* a_ptr = A + (size_t)ga_row * KTOT + a_col;
  ushort* as_w = As + a_row * LDA + a_col;

  // B staging: thread covers 8 k-rows x 2 n-cols via 8 coalesced float2 loads,
  // converts f32->bf16, writes two aligned b128s into k-blocked LDS layout.
  int n2 = (tid & 31) * 2;   // [0,64) even
  int kb = tid >> 5;         // [0,8)
  const float* w_ptr = W + (size_t)e * KTOT * NTOT + (size_t)kb * 8 * NTOT + (n0 + n2);
  ushort* bs_w = Bs + (kb * 64 + n2) * 8;

  const ushort* as_r = As + (mw + fm) * LDA + quad * 8;

  for (int k0 = 0; k0 < KTOT; k0 += BK) {
    uint4 av = *(const uint4*)(a_ptr + k0);
    union { ushort u16[8]; uint4 v; } ca, cb;
    const float* wp = w_ptr + (size_t)k0 * NTOT;
#pragma unroll
    for (int j = 0; j < 8; j++) {
      float2 u = *(const float2*)(wp + (size_t)j * NTOT);  // cols n2,n2+1 of k-row kb*8+j
      ca.u16[j] = f2bf(u.x);
      cb.u16[j] = f2bf(u.y);
    }
    *(uint4*)as_w = av;
    *(uint4*)bs_w = ca.v;         // Bs[kb][n2][0..8)
    *(uint4*)(bs_w + 8) = cb.v;   // Bs[kb][n2+1][0..8)
    __syncthreads();
#pragma unroll
    for (int ks = 0; ks < 2; ks++) {
      bf16x8 af  = *(const bf16x8*)(as_r + ks * 32);
      bf16x8 bf0 = *(const bf16x8*)(Bs + ((quad + 4 * ks) * 64 + nw + fm) * 8);
      bf16x8 bf1 = *(const bf16x8*)(Bs + ((quad + 4 * ks) * 64 + nw + 16 + fm) * 8);
      acc0 = __builtin_amdgcn_mfma_f32_16x16x32_bf16(af, bf0, acc0, 0, 0, 0);
      acc1 = __builtin_amdgcn_mfma_f32_16x16x32_bf16(af, bf1, acc1, 0, 0, 0);
    }
    __syncthreads();
  }

  // C/D layout: col = lane&15, row = quad*4 + reg (m89/m91 verified)
  int lm_base = mt * 32 + mw + quad * 4;
#pragma unroll
  for (int r = 0; r < 4; r++) {
    int lm = lm_base + r;
    if (lm >= ce) continue;
    int grow = offs[e] + lm;
#pragma unroll
    for (int sub = 0; sub < 2; sub++) {
      int gcol = n0 + nw + sub * 16 + fm;
      float v = sub ? acc1[r] : acc0[r];
      if (MODE == 1) {
        v += bias[e * NTOT + gcol];
        v = v > 0.f ? v : 0.f;
        CoutH[(size_t)grow * NTOT + gcol] = f2bf(v);
      } else {
        int t = perm[grow];
        float al = alphav[t];
        v = xin[(size_t)t * NTOT + gcol] + al * (v + bias[e * NTOT + gcol]);
        CoutF[(size_t)t * NTOT + gcol] = v;
      }
    }
  }
}

extern "C" void kernel_launch(void* const* d_in, const int* in_sizes, int n_in,
                              void* d_out, int out_size, void* d_ws, size_t ws_size,
                              hipStream_t stream) {
  const float* x    = (const float*)d_in[0];
  const float* cent = (const float*)d_in[1];
  const float* ln_g = (const float*)d_in[2];
  const float* ln_b = (const float*)d_in[3];
  const float* W1   = (const float*)d_in[4];
  const float* b1   = (const float*)d_in[5];
  const float* W2   = (const float*)d_in[6];
  const float* b2   = (const float*)d_in[7];
  float* out = (float*)d_out;

  char* ws = (char*)d_ws;
  size_t off = 0;
  auto alloc = [&](size_t bytes) {
    char* p = ws + off;
    off += (bytes + 255) & ~(size_t)255;
    return p;
  };
  // small control arrays first (total ws ~10.1 MB)
  int*   eid    = (int*)alloc(T_TOK * 4);
  float* alphav = (float*)alloc(T_TOK * 4);
  float* muv    = (float*)alloc(T_TOK * 4);
  float* rsigv  = (float*)alloc(T_TOK * 4);
  int*   posof  = (int*)alloc(T_TOK * 4);
  int*   perm   = (int*)alloc(T_TOK * 4);
  int*   cnt    = (int*)alloc(E_NUM * 4);
  int*   offs   = (int*)alloc(E_NUM * 4);
  ushort* h0p   = (ushort*)alloc((size_t)T_TOK * D_DIM * 2);  // 2 MB bf16
  ushort* H     = (ushort*)alloc((size_t)T_TOK * F_DIM * 2);  // 8 MB bf16

  hipLaunchKernelGGL(router_kernel, dim3(T_TOK / 4), dim3(256), 0, stream,
                     x, cent, eid, alphav, muv, rsigv);
  hipLaunchKernelGGL(perm_kernel, dim3(1), dim3(1024), 0, stream,
                     eid, perm, posof, cnt, offs);
  hipLaunchKernelGGL(ln_apply_kernel, dim3(T_TOK), dim3(64), 0, stream,
                     x, ln_g, ln_b, eid, muv, rsigv, posof, h0p);
  hipLaunchKernelGGL((moe_gemm_kernel<D_DIM, F_DIM, 1>), dim3(F_DIM / 64, T_TOK / 32, E_NUM), dim3(256), 0, stream,
                     h0p, W1, b1, cnt, offs, perm, alphav, x, H, nullptr);
  hipLaunchKernelGGL((moe_gemm_kernel<F_DIM, D_DIM, 2>), dim3(D_DIM / 64, T_TOK / 32, E_NUM), dim3(256), 0, stream,
                     H, W2, b2, cnt, offs, perm, alphav, x, nullptr, out);
}

// Round 4
// 185.312 us; speedup vs baseline: 1.1717x; 1.1717x over previous
//
#include <hip/hip_runtime.h>

#define T_TOK 2048
#define D_DIM 512
#define F_DIM 2048
#define E_NUM 8
#define LN_EPS 1e-5f

typedef __attribute__((ext_vector_type(8))) short bf16x8;
typedef __attribute__((ext_vector_type(4))) float floatx4;

static __device__ __forceinline__ ushort f2bf(float f) {
  union { float f; unsigned int u; } v; v.f = f;
  unsigned int u = v.u;
  return (ushort)((u + 0x7fffu + ((u >> 16) & 1u)) >> 16);  // RNE
}

static __device__ __forceinline__ void gld_lds16(const void* g, void* l) {
  __builtin_amdgcn_global_load_lds(
      (const __attribute__((address_space(1))) unsigned int*)g,
      (__attribute__((address_space(3))) unsigned int*)l, 16, 0, 0);
}

// ---------------- router: per-token expert argmax + alpha + LN stats ----------------
__global__ __launch_bounds__(256) void router_kernel(
    const float* __restrict__ x, const float* __restrict__ cent,
    int* __restrict__ eid, float* __restrict__ alphav,
    float* __restrict__ muv, float* __restrict__ rsigv) {
  int wave = threadIdx.x >> 6, lane = threadIdx.x & 63;
  int t = blockIdx.x * 4 + wave;
  const float* xp = x + (size_t)t * D_DIM + lane * 8;
  float4 x0 = *(const float4*)xp, x1 = *(const float4*)(xp + 4);
  float xv[8] = {x0.x, x0.y, x0.z, x0.w, x1.x, x1.y, x1.z, x1.w};
  float s = 0.f, s2 = 0.f, cd[E_NUM];
#pragma unroll
  for (int j = 0; j < 8; j++) { s += xv[j]; s2 += xv[j] * xv[j]; }
#pragma unroll
  for (int e = 0; e < E_NUM; e++) {
    const float* cp = cent + (size_t)e * D_DIM + lane * 8;
    float4 c0 = *(const float4*)cp, c1 = *(const float4*)(cp + 4);
    float cv[8] = {c0.x, c0.y, c0.z, c0.w, c1.x, c1.y, c1.z, c1.w};
    float a = 0.f;
#pragma unroll
    for (int j = 0; j < 8; j++) a += xv[j] * cv[j];
    cd[e] = a;
  }
#pragma unroll
  for (int m = 1; m < 64; m <<= 1) {
    s  += __shfl_xor(s,  m, 64);
    s2 += __shfl_xor(s2, m, 64);
#pragma unroll
    for (int e = 0; e < E_NUM; e++) cd[e] += __shfl_xor(cd[e], m, 64);
  }
  if (lane == 0) {
    float mu = s / (float)D_DIM;
    float var = s2 / (float)D_DIM - mu * mu;
    if (var < 0.f) var = 0.f;
    int best = 0;
#pragma unroll
    for (int e = 1; e < E_NUM; e++) if (cd[e] > cd[best]) best = e;  // first-max (np.argmax)
    eid[t] = best;
    alphav[t] = 1.f / (1.f + expf(-cd[best]));
    muv[t] = mu;
    rsigv[t] = rsqrtf(var + LN_EPS);
  }
}

// ---------------- build permutation ----------------
__global__ __launch_bounds__(1024) void perm_kernel(
    const int* __restrict__ eid, int* __restrict__ perm, int* __restrict__ posof,
    int* __restrict__ cnt_g, int* __restrict__ offs_g) {
  __shared__ int cnt[E_NUM], offs[E_NUM], cur[E_NUM];
  if (threadIdx.x < E_NUM) cnt[threadIdx.x] = 0;
  __syncthreads();
  for (int t = threadIdx.x; t < T_TOK; t += 1024) atomicAdd(&cnt[eid[t]], 1);
  __syncthreads();
  if (threadIdx.x == 0) {
    int a = 0;
    for (int e = 0; e < E_NUM; e++) { offs[e] = a; cur[e] = a; a += cnt[e]; }
  }
  __syncthreads();
  for (int t = threadIdx.x; t < T_TOK; t += 1024) {
    int e = eid[t];
    int p = atomicAdd(&cur[e], 1);
    perm[p] = t;
    posof[t] = p;
  }
  if (threadIdx.x < E_NUM) { cnt_g[threadIdx.x] = cnt[threadIdx.x]; offs_g[threadIdx.x] = offs[threadIdx.x]; }
}

// ---------------- LN apply -> bf16 h0 (permuted rows) ----------------
__global__ __launch_bounds__(64) void ln_apply_kernel(
    const float* __restrict__ x, const float* __restrict__ g, const float* __restrict__ b,
    const int* __restrict__ eid, const float* __restrict__ muv, const float* __restrict__ rsigv,
    const int* __restrict__ posof, ushort* __restrict__ h0p) {
  int t = blockIdx.x, lane = threadIdx.x;
  int e = eid[t];
  float mu = muv[t], rs = rsigv[t];
  int pos = posof[t];
  int c0 = lane * 8;
  const float* xp = x + (size_t)t * D_DIM + c0;
  const float* gp = g + (size_t)e * D_DIM + c0;
  const float* bp = b + (size_t)e * D_DIM + c0;
  union { ushort u16[8]; uint4 v; } o;
#pragma unroll
  for (int j = 0; j < 8; j++)
    o.u16[j] = f2bf((xp[j] - mu) * rs * gp[j] + bp[j]);
  *(uint4*)(h0p + (size_t)pos * D_DIM + c0) = o.v;
}

// ---------------- fused transpose+convert: src f32 [R][C] -> dst bf16 [C][R], per expert ----------------
__global__ __launch_bounds__(256) void convT_kernel(
    const float* __restrict__ src, ushort* __restrict__ dst, int R, int C) {
  __shared__ ushort tile[64][34];  // [c][r]
  int e = blockIdx.z;
  const float* s = src + (size_t)e * R * C;
  ushort* d = dst + (size_t)e * R * C;
  int c0 = blockIdx.x * 64, r0 = blockIdx.y * 32;
  int tid = threadIdx.x;
  int tc = (tid & 31) * 2, tr = tid >> 5;  // tr in [0,8)
#pragma unroll
  for (int rr = 0; rr < 32; rr += 8) {
    float2 v = *(const float2*)(s + (size_t)(r0 + tr + rr) * C + c0 + tc);
    tile[tc][tr + rr] = f2bf(v.x);
    tile[tc + 1][tr + rr] = f2bf(v.y);
  }
  __syncthreads();
  int wc = tid >> 4, wj = (tid & 15) * 2;  // wc in [0,16), wj row pair
#pragma unroll
  for (int cc = 0; cc < 64; cc += 16) {
    uint v = (uint)tile[cc + wc][wj] | ((uint)tile[cc + wc][wj + 1] << 16);
    *(uint*)(d + (size_t)(c0 + cc + wc) * R + r0 + wj) = v;
  }
}

// ---------------- out = x + alpha * b2[expert]  (bias pre-add for split-K GEMM2) ----------------
__global__ __launch_bounds__(128) void init_out_kernel(
    const float* __restrict__ x, const float* __restrict__ b2,
    const int* __restrict__ eid, const float* __restrict__ alphav,
    float* __restrict__ out) {
  int t = blockIdx.x;
  float al = alphav[t];
  int e = eid[t];
  int c = threadIdx.x * 4;
  float4 xv = *(const float4*)(x + (size_t)t * D_DIM + c);
  float4 bv = *(const float4*)(b2 + (size_t)e * D_DIM + c);
  float4 o = {xv.x + al * bv.x, xv.y + al * bv.y, xv.z + al * bv.z, xv.w + al * bv.w};
  *(float4*)(out + (size_t)t * D_DIM + c) = o;
}

// ---------------- grouped GEMM, m97 structure: 128x128 tile, BK=64, global_load_lds ----------------
// A: [T][KTOT] bf16 rows grouped by expert. BT: [E][NTOT][KTOT] bf16 (B^T).
// MODE 1: H = relu(A*W1 + b1) bf16, KTOT=512, NTOT=2048, kiters=8, bx = nt (16)
// MODE 2: split-K=4: out[t] += alpha[t]*partial, KTOT=2048, NTOT=512, bx = slice*4 + nt
template<int KTOT, int NTOT, int MODE>
__global__ __launch_bounds__(256) void moe_gemm_kernel(
    const ushort* __restrict__ A, const ushort* __restrict__ BT,
    const float* __restrict__ bias,
    const int* __restrict__ cnt, const int* __restrict__ offs,
    const int* __restrict__ perm, const float* __restrict__ alphav,
    ushort* __restrict__ Hout, float* __restrict__ outF) {
  constexpr int BK = 64;
  constexpr int KITER = 8;  // MODE1: full K=512; MODE2: one 512-slice of K=2048
  int e = blockIdx.z, mt = blockIdx.y;
  int ce = cnt[e];
  if (mt * 128 >= ce) return;  // uniform early-exit before any barrier
  int bx = blockIdx.x;
  int nt = (MODE == 1) ? bx : (bx & 3);
  int k_base = (MODE == 1) ? 0 : (bx >> 2) * 512;
  int n0 = nt * 128;
  int rowbase = offs[e] + mt * 128;

  __shared__ ushort As[128 * 64];  // [m][k] row-major (128B rows, m97 layout)
  __shared__ ushort Bs[128 * 64];  // [n][k]

  int tid = threadIdx.x;
  int lane = tid & 63, wave = tid >> 6;
  int mw = (wave & 1) * 64, nw = (wave >> 1) * 64;  // wave's 64x64 sub-tile
  int fm = lane & 15, quad = lane >> 4;

  // staging addresses: round r covers rows [r*32, r*32+32), thread -> row tid>>3, col8 (tid&7)*8
  int srow = tid >> 3, scol = (tid & 7) * 8;
  const ushort* a_gp[4];
  const ushort* b_gp[4];
#pragma unroll
  for (int r = 0; r < 4; r++) {
    int ar = rowbase + r * 32 + srow;
    if (ar > T_TOK - 1) ar = T_TOK - 1;  // clamp; masked on store
    a_gp[r] = A + (size_t)ar * KTOT + k_base + scol;
    b_gp[r] = BT + ((size_t)e * NTOT + n0 + r * 32 + srow) * KTOT + k_base + scol;
  }
  char* as_l = (char*)As + wave * 1024;  // wave-uniform LDS base (+ r*4096)
  char* bs_l = (char*)Bs + wave * 1024;

  floatx4 acc[4][4];
#pragma unroll
  for (int i = 0; i < 4; i++)
#pragma unroll
    for (int j = 0; j < 4; j++) acc[i][j] = (floatx4){0.f, 0.f, 0.f, 0.f};

  for (int ki = 0; ki < KITER; ki++) {
    int k0 = ki * BK;
#pragma unroll
    for (int r = 0; r < 4; r++) {
      gld_lds16(a_gp[r] + k0, as_l + r * 4096);
      gld_lds16(b_gp[r] + k0, bs_l + r * 4096);
    }
    __syncthreads();
#pragma unroll
    for (int ks = 0; ks < 2; ks++) {
      bf16x8 af[4], bfr[4];
#pragma unroll
      for (int i = 0; i < 4; i++) {
        af[i]  = *(const bf16x8*)(As + (mw + i * 16 + fm) * 64 + ks * 32 + quad * 8);
        bfr[i] = *(const bf16x8*)(Bs + (nw + i * 16 + fm) * 64 + ks * 32 + quad * 8);
      }
#pragma unroll
      for (int mi = 0; mi < 4; mi++)
#pragma unroll
        for (int ni = 0; ni < 4; ni++)
          acc[mi][ni] = __builtin_amdgcn_mfma_f32_16x16x32_bf16(af[mi], bfr[ni], acc[mi][ni], 0, 0, 0);
    }
    __syncthreads();
  }

  // C/D layout: col = lane&15, row = quad*4 + reg (m89/m91 verified)
  if (MODE == 1) {
    float bv[4];
#pragma unroll
    for (int ni = 0; ni < 4; ni++) bv[ni] = bias[e * NTOT + n0 + nw + ni * 16 + fm];
#pragma unroll
    for (int mi = 0; mi < 4; mi++) {
      int lmb = mt * 128 + mw + mi * 16 + quad * 4;
#pragma unroll
      for (int r = 0; r < 4; r++) {
        int lm = lmb + r;
        if (lm >= ce) continue;
        size_t row = (size_t)(offs[e] + lm);
#pragma unroll
        for (int ni = 0; ni < 4; ni++) {
          float v = acc[mi][ni][r] + bv[ni];
          v = v > 0.f ? v : 0.f;
          Hout[row * NTOT + n0 + nw + ni * 16 + fm] = f2bf(v);
        }
      }
    }
  } else {
#pragma unroll
    for (int mi = 0; mi < 4; mi++) {
      int lmb = mt * 128 + mw + mi * 16 + quad * 4;
#pragma unroll
      for (int r = 0; r < 4; r++) {
        int lm = lmb + r;
        if (lm >= ce) continue;
        int t = perm[offs[e] + lm];
        float al = alphav[t];
#pragma unroll
        for (int ni = 0; ni < 4; ni++)
          atomicAdd(&outF[(size_t)t * NTOT + n0 + nw + ni * 16 + fm], al * acc[mi][ni][r]);
      }
    }
  }
}

extern "C" void kernel_launch(void* const* d_in, const int* in_sizes, int n_in,
                              void* d_out, int out_size, void* d_ws, size_t ws_size,
                              hipStream_t stream) {
  const float* x    = (const float*)d_in[0];
  const float* cent = (const float*)d_in[1];
  const float* ln_g = (const float*)d_in[2];
  const float* ln_b = (const float*)d_in[3];
  const float* W1   = (const float*)d_in[4];
  const float* b1   = (const float*)d_in[5];
  const float* W2   = (const float*)d_in[6];
  const float* b2   = (const float*)d_in[7];
  float* out = (float*)d_out;

  char* ws = (char*)d_ws;
  size_t off = 0;
  auto alloc = [&](size_t bytes) {
    char* p = ws + off;
    off += (bytes + 255) & ~(size_t)255;
    return p;
  };
  int*   eid    = (int*)alloc(T_TOK * 4);
  float* alphav = (float*)alloc(T_TOK * 4);
  float* muv    = (float*)alloc(T_TOK * 4);
  float* rsigv  = (float*)alloc(T_TOK * 4);
  int*   posof  = (int*)alloc(T_TOK * 4);
  int*   perm   = (int*)alloc(T_TOK * 4);
  int*   cnt    = (int*)alloc(E_NUM * 4);
  int*   offs   = (int*)alloc(E_NUM * 4);
  ushort* h0p   = (ushort*)alloc((size_t)T_TOK * D_DIM * 2);            // 2 MB bf16
  ushort* H     = (ushort*)alloc((size_t)T_TOK * F_DIM * 2);            // 8 MB bf16
  ushort* W1T   = (ushort*)alloc((size_t)E_NUM * F_DIM * D_DIM * 2);    // 16.8 MB bf16 [E][F][D]
  ushort* W2T   = (ushort*)alloc((size_t)E_NUM * D_DIM * F_DIM * 2);    // 16.8 MB bf16 [E][D][F]

  hipLaunchKernelGGL(router_kernel, dim3(T_TOK / 4), dim3(256), 0, stream,
                     x, cent, eid, alphav, muv, rsigv);
  hipLaunchKernelGGL(perm_kernel, dim3(1), dim3(1024), 0, stream,
                     eid, perm, posof, cnt, offs);
  hipLaunchKernelGGL(ln_apply_kernel, dim3(T_TOK), dim3(64), 0, stream,
                     x, ln_g, ln_b, eid, muv, rsigv, posof, h0p);
  // W1 [E][D][F] -> W1T [E][F][D]; W2 [E][F][D] -> W2T [E][D][F]
  hipLaunchKernelGGL(convT_kernel, dim3(F_DIM / 64, D_DIM / 32, E_NUM), dim3(256), 0, stream,
                     W1, W1T, D_DIM, F_DIM);
  hipLaunchKernelGGL(convT_kernel, dim3(D_DIM / 64, F_DIM / 32, E_NUM), dim3(256), 0, stream,
                     W2, W2T, F_DIM, D_DIM);
  hipLaunchKernelGGL(init_out_kernel, dim3(T_TOK), dim3(128), 0, stream,
                     x, b2, eid, alphav, out);
  hipLaunchKernelGGL((moe_gemm_kernel<D_DIM, F_DIM, 1>), dim3(F_DIM / 128, T_TOK / 128, E_NUM), dim3(256), 0, stream,
                     h0p, W1T, b1, cnt, offs, perm, alphav, H, nullptr);
  hipLaunchKernelGGL((moe_gemm_kernel<F_DIM, D_DIM, 2>), dim3(4 * 4, T_TOK / 128, E_NUM), dim3(256), 0, stream,
                     H, W2T, b2, cnt, offs, perm, alphav, nullptr, out);
}

// Round 5
// 167.620 us; speedup vs baseline: 1.2954x; 1.1056x over previous
//
#include <hip/hip_runtime.h>

#define T_TOK 2048
#define D_DIM 512
#define F_DIM 2048
#define E_NUM 8
#define LN_EPS 1e-5f

typedef __attribute__((ext_vector_type(8))) short bf16x8;
typedef __attribute__((ext_vector_type(4))) float floatx4;

static __device__ __forceinline__ ushort f2bf(float f) {
  union { float f; unsigned int u; } v; v.f = f;
  unsigned int u = v.u;
  return (ushort)((u + 0x7fffu + ((u >> 16) & 1u)) >> 16);  // RNE
}

static __device__ __forceinline__ void gld_lds16(const void* g, void* l) {
  __builtin_amdgcn_global_load_lds(
      (const __attribute__((address_space(1))) unsigned int*)g,
      (__attribute__((address_space(3))) unsigned int*)l, 16, 0, 0);
}

// ---------------- router: per-token expert argmax + alpha + LN stats ----------------
__global__ __launch_bounds__(256) void router_kernel(
    const float* __restrict__ x, const float* __restrict__ cent,
    int* __restrict__ eid, float* __restrict__ alphav,
    float* __restrict__ muv, float* __restrict__ rsigv) {
  int wave = threadIdx.x >> 6, lane = threadIdx.x & 63;
  int t = blockIdx.x * 4 + wave;
  const float* xp = x + (size_t)t * D_DIM + lane * 8;
  float4 x0 = *(const float4*)xp, x1 = *(const float4*)(xp + 4);
  float xv[8] = {x0.x, x0.y, x0.z, x0.w, x1.x, x1.y, x1.z, x1.w};
  float s = 0.f, s2 = 0.f, cd[E_NUM];
#pragma unroll
  for (int j = 0; j < 8; j++) { s += xv[j]; s2 += xv[j] * xv[j]; }
#pragma unroll
  for (int e = 0; e < E_NUM; e++) {
    const float* cp = cent + (size_t)e * D_DIM + lane * 8;
    float4 c0 = *(const float4*)cp, c1 = *(const float4*)(cp + 4);
    float cv[8] = {c0.x, c0.y, c0.z, c0.w, c1.x, c1.y, c1.z, c1.w};
    float a = 0.f;
#pragma unroll
    for (int j = 0; j < 8; j++) a += xv[j] * cv[j];
    cd[e] = a;
  }
#pragma unroll
  for (int m = 1; m < 64; m <<= 1) {
    s  += __shfl_xor(s,  m, 64);
    s2 += __shfl_xor(s2, m, 64);
#pragma unroll
    for (int e = 0; e < E_NUM; e++) cd[e] += __shfl_xor(cd[e], m, 64);
  }
  if (lane == 0) {
    float mu = s / (float)D_DIM;
    float var = s2 / (float)D_DIM - mu * mu;
    if (var < 0.f) var = 0.f;
    int best = 0;
#pragma unroll
    for (int e = 1; e < E_NUM; e++) if (cd[e] > cd[best]) best = e;  // first-max (np.argmax)
    eid[t] = best;
    alphav[t] = 1.f / (1.f + expf(-cd[best]));
    muv[t] = mu;
    rsigv[t] = rsqrtf(var + LN_EPS);
  }
}

// ---------------- build permutation ----------------
__global__ __launch_bounds__(1024) void perm_kernel(
    const int* __restrict__ eid, int* __restrict__ perm, int* __restrict__ posof,
    int* __restrict__ cnt_g, int* __restrict__ offs_g) {
  __shared__ int cnt[E_NUM], offs[E_NUM], cur[E_NUM];
  if (threadIdx.x < E_NUM) cnt[threadIdx.x] = 0;
  __syncthreads();
  for (int t = threadIdx.x; t < T_TOK; t += 1024) atomicAdd(&cnt[eid[t]], 1);
  __syncthreads();
  if (threadIdx.x == 0) {
    int a = 0;
    for (int e = 0; e < E_NUM; e++) { offs[e] = a; cur[e] = a; a += cnt[e]; }
  }
  __syncthreads();
  for (int t = threadIdx.x; t < T_TOK; t += 1024) {
    int e = eid[t];
    int p = atomicAdd(&cur[e], 1);
    perm[p] = t;
    posof[t] = p;
  }
  if (threadIdx.x < E_NUM) { cnt_g[threadIdx.x] = cnt[threadIdx.x]; offs_g[threadIdx.x] = offs[threadIdx.x]; }
}

// ---------------- LN apply -> bf16 h0 (permuted rows) ----------------
__global__ __launch_bounds__(64) void ln_apply_kernel(
    const float* __restrict__ x, const float* __restrict__ g, const float* __restrict__ b,
    const int* __restrict__ eid, const float* __restrict__ muv, const float* __restrict__ rsigv,
    const int* __restrict__ posof, ushort* __restrict__ h0p) {
  int t = blockIdx.x, lane = threadIdx.x;
  int e = eid[t];
  float mu = muv[t], rs = rsigv[t];
  int pos = posof[t];
  int c0 = lane * 8;
  const float* xp = x + (size_t)t * D_DIM + c0;
  const float* gp = g + (size_t)e * D_DIM + c0;
  const float* bp = b + (size_t)e * D_DIM + c0;
  union { ushort u16[8]; uint4 v; } o;
#pragma unroll
  for (int j = 0; j < 8; j++)
    o.u16[j] = f2bf((xp[j] - mu) * rs * gp[j] + bp[j]);
  *(uint4*)(h0p + (size_t)pos * D_DIM + c0) = o.v;
}

// ---------------- fused transpose+convert: src f32 [R][C] -> dst bf16 [C][R], per expert ----------------
__global__ __launch_bounds__(256) void convT_kernel(
    const float* __restrict__ src, ushort* __restrict__ dst, int R, int C) {
  __shared__ ushort tile[64][34];  // [c][r]
  int e = blockIdx.z;
  const float* s = src + (size_t)e * R * C;
  ushort* d = dst + (size_t)e * R * C;
  int c0 = blockIdx.x * 64, r0 = blockIdx.y * 32;
  int tid = threadIdx.x;
  int tc = (tid & 31) * 2, tr = tid >> 5;  // tr in [0,8)
#pragma unroll
  for (int rr = 0; rr < 32; rr += 8) {
    float2 v = *(const float2*)(s + (size_t)(r0 + tr + rr) * C + c0 + tc);
    tile[tc][tr + rr] = f2bf(v.x);
    tile[tc + 1][tr + rr] = f2bf(v.y);
  }
  __syncthreads();
  int wc = tid >> 4, wj = (tid & 15) * 2;  // wc in [0,16), wj row pair
#pragma unroll
  for (int cc = 0; cc < 64; cc += 16) {
    uint v = (uint)tile[cc + wc][wj] | ((uint)tile[cc + wc][wj + 1] << 16);
    *(uint*)(d + (size_t)(c0 + cc + wc) * R + r0 + wj) = v;
  }
}

// ---------------- final reduce: out = x + alpha * (sum of split-K partials + b2) ----------------
__global__ __launch_bounds__(128) void reduce_kernel(
    const float* __restrict__ P, const float* __restrict__ x, const float* __restrict__ b2,
    const int* __restrict__ eid, const float* __restrict__ alphav, const int* __restrict__ posof,
    float* __restrict__ out) {
  int t = blockIdx.x;
  int e = eid[t];
  float al = alphav[t];
  size_t pos = (size_t)posof[t];
  int c = threadIdx.x * 4;
  const size_t stride = (size_t)T_TOK * D_DIM;
  float4 s0 = *(const float4*)(P + pos * D_DIM + c);
  float4 s1 = *(const float4*)(P + stride + pos * D_DIM + c);
  float4 s2 = *(const float4*)(P + 2 * stride + pos * D_DIM + c);
  float4 s3 = *(const float4*)(P + 3 * stride + pos * D_DIM + c);
  float4 bv = *(const float4*)(b2 + (size_t)e * D_DIM + c);
  float4 xv = *(const float4*)(x + (size_t)t * D_DIM + c);
  float4 o;
  o.x = xv.x + al * (s0.x + s1.x + s2.x + s3.x + bv.x);
  o.y = xv.y + al * (s0.y + s1.y + s2.y + s3.y + bv.y);
  o.z = xv.z + al * (s0.z + s1.z + s2.z + s3.z + bv.z);
  o.w = xv.w + al * (s0.w + s1.w + s2.w + s3.w + bv.w);
  *(float4*)(out + (size_t)t * D_DIM + c) = o;
}

// ---------------- grouped GEMM, m97 structure + XOR bank swizzle ----------------
// LDS layout: LDS[row][c8 ^ (row&7)] holds global col8=c8 (16B units). DMA stays
// lane-contiguous (lane's GLOBAL col = (lane&7)^(row&7)); frag reads spread over
// 8 bank-groups -> 2-way aliasing (free, m136) instead of 16-way.
// MODE 1: H = relu(A*W1 + b1) bf16. KTOT=512, NTOT=2048, bx = nt (16).
// MODE 2: partials P[slice][row][*] = A*W2 slice-sum. KTOT=2048, NTOT=512, bx = slice*4+nt.
template<int KTOT, int NTOT, int MODE>
__global__ __launch_bounds__(256) void moe_gemm_kernel(
    const ushort* __restrict__ A, const ushort* __restrict__ BT,
    const float* __restrict__ bias,
    const int* __restrict__ cnt, const int* __restrict__ offs,
    ushort* __restrict__ Hout, float* __restrict__ Pout) {
  constexpr int BK = 64;
  constexpr int KITER = 8;  // MODE1: full K=512; MODE2: one 512-slice of K=2048
  int e = blockIdx.z, mt = blockIdx.y;
  int ce = cnt[e];
  if (mt * 128 >= ce) return;  // uniform early-exit before any barrier
  int bx = blockIdx.x;
  int nt = (MODE == 1) ? bx : (bx & 3);
  int k_base = (MODE == 1) ? 0 : (bx >> 2) * 512;
  int n0 = nt * 128;
  int rowbase = offs[e] + mt * 128;

  __shared__ ushort As[128 * 64];  // [m][64], 16B-unit cols XOR-swizzled by (m&7)
  __shared__ ushort Bs[128 * 64];  // [n][64], same swizzle

  int tid = threadIdx.x;
  int lane = tid & 63, wave = tid >> 6;
  int mw = (wave & 1) * 64, nw = (wave >> 1) * 64;  // wave's 64x64 sub-tile
  int fm = lane & 15, quad = lane >> 4;
  int fm7 = fm & 7;

  // staging: round r covers rows [r*32, r*32+32); thread -> row tid>>3,
  // global col8 = (tid&7) ^ (row&7)  (so LDS slot (tid&7) holds swizzled data)
  int srow = tid >> 3;
  int scol = (((tid & 7) ^ (srow & 7)) * 8);
  const ushort* a_gp[4];
  const ushort* b_gp[4];
#pragma unroll
  for (int r = 0; r < 4; r++) {
    int ar = rowbase + r * 32 + srow;
    if (ar > T_TOK - 1) ar = T_TOK - 1;  // clamp; masked on store
    a_gp[r] = A + (size_t)ar * KTOT + k_base + scol;
    b_gp[r] = BT + ((size_t)e * NTOT + n0 + r * 32 + srow) * KTOT + k_base + scol;
  }
  char* as_l = (char*)As + wave * 1024;  // wave-uniform LDS base (+ r*4096)
  char* bs_l = (char*)Bs + wave * 1024;

  floatx4 acc[4][4];
#pragma unroll
  for (int i = 0; i < 4; i++)
#pragma unroll
    for (int j = 0; j < 4; j++) acc[i][j] = (floatx4){0.f, 0.f, 0.f, 0.f};

  for (int ki = 0; ki < KITER; ki++) {
    int k0 = ki * BK;
#pragma unroll
    for (int r = 0; r < 4; r++) {
      gld_lds16(a_gp[r] + k0, as_l + r * 4096);
      gld_lds16(b_gp[r] + k0, bs_l + r * 4096);
    }
    __syncthreads();
#pragma unroll
    for (int ks = 0; ks < 2; ks++) {
      int c8 = ((ks * 4 + quad) ^ fm7) * 8;  // swizzled 16B-col within the 64-elem row
      bf16x8 af[4], bfr[4];
#pragma unroll
      for (int i = 0; i < 4; i++) {
        af[i]  = *(const bf16x8*)(As + (mw + i * 16 + fm) * 64 + c8);
        bfr[i] = *(const bf16x8*)(Bs + (nw + i * 16 + fm) * 64 + c8);
      }
#pragma unroll
      for (int mi = 0; mi < 4; mi++)
#pragma unroll
        for (int ni = 0; ni < 4; ni++)
          acc[mi][ni] = __builtin_amdgcn_mfma_f32_16x16x32_bf16(af[mi], bfr[ni], acc[mi][ni], 0, 0, 0);
    }
    __syncthreads();
  }

  // C/D layout: col = lane&15, row = quad*4 + reg (m89/m91 verified)
  if (MODE == 1) {
    float bv[4];
#pragma unroll
    for (int ni = 0; ni < 4; ni++) bv[ni] = bias[e * NTOT + n0 + nw + ni * 16 + fm];
#pragma unroll
    for (int mi = 0; mi < 4; mi++) {
      int lmb = mt * 128 + mw + mi * 16 + quad * 4;
#pragma unroll
      for (int r = 0; r < 4; r++) {
        int lm = lmb + r;
        if (lm >= ce) continue;
        size_t row = (size_t)(offs[e] + lm);
#pragma unroll
        for (int ni = 0; ni < 4; ni++) {
          float v = acc[mi][ni][r] + bv[ni];
          v = v > 0.f ? v : 0.f;
          Hout[row * NTOT + n0 + nw + ni * 16 + fm] = f2bf(v);
        }
      }
    }
  } else {
    float* dst = Pout + (size_t)(bx >> 2) * T_TOK * NTOT;  // slice base
#pragma unroll
    for (int mi = 0; mi < 4; mi++) {
      int lmb = mt * 128 + mw + mi * 16 + quad * 4;
#pragma unroll
      for (int r = 0; r < 4; r++) {
        int lm = lmb + r;
        if (lm >= ce) continue;
        size_t row = (size_t)(offs[e] + lm);
#pragma unroll
        for (int ni = 0; ni < 4; ni++)
          dst[row * NTOT + n0 + nw + ni * 16 + fm] = acc[mi][ni][r];
      }
    }
  }
}

extern "C" void kernel_launch(void* const* d_in, const int* in_sizes, int n_in,
                              void* d_out, int out_size, void* d_ws, size_t ws_size,
                              hipStream_t stream) {
  const float* x    = (const float*)d_in[0];
  const float* cent = (const float*)d_in[1];
  const float* ln_g = (const float*)d_in[2];
  const float* ln_b = (const float*)d_in[3];
  const float* W1   = (const float*)d_in[4];
  const float* b1   = (const float*)d_in[5];
  const float* W2   = (const float*)d_in[6];
  const float* b2   = (const float*)d_in[7];
  float* out = (float*)d_out;

  char* ws = (char*)d_ws;
  size_t off = 0;
  auto alloc = [&](size_t bytes) {
    char* p = ws + off;
    off += (bytes + 255) & ~(size_t)255;
    return p;
  };
  int*   eid    = (int*)alloc(T_TOK * 4);
  float* alphav = (float*)alloc(T_TOK * 4);
  float* muv    = (float*)alloc(T_TOK * 4);
  float* rsigv  = (float*)alloc(T_TOK * 4);
  int*   posof  = (int*)alloc(T_TOK * 4);
  int*   perm   = (int*)alloc(T_TOK * 4);
  int*   cnt    = (int*)alloc(E_NUM * 4);
  int*   offs   = (int*)alloc(E_NUM * 4);
  ushort* h0p   = (ushort*)alloc((size_t)T_TOK * D_DIM * 2);           // 2 MB bf16
  ushort* H     = (ushort*)alloc((size_t)T_TOK * F_DIM * 2);           // 8 MB bf16
  ushort* W1T   = (ushort*)alloc((size_t)E_NUM * F_DIM * D_DIM * 2);   // 16.8 MB bf16 [E][F][D]
  ushort* W2T   = (ushort*)alloc((size_t)E_NUM * D_DIM * F_DIM * 2);   // 16.8 MB bf16 [E][D][F]
  float*  Part  = (float*)alloc((size_t)4 * T_TOK * D_DIM * 4);        // 16.8 MB f32 split-K partials

  hipLaunchKernelGGL(router_kernel, dim3(T_TOK / 4), dim3(256), 0, stream,
                     x, cent, eid, alphav, muv, rsigv);
  hipLaunchKernelGGL(perm_kernel, dim3(1), dim3(1024), 0, stream,
                     eid, perm, posof, cnt, offs);
  hipLaunchKernelGGL(ln_apply_kernel, dim3(T_TOK), dim3(64), 0, stream,
                     x, ln_g, ln_b, eid, muv, rsigv, posof, h0p);
  // W1 [E][D][F] -> W1T [E][F][D]; W2 [E][F][D] -> W2T [E][D][F]
  hipLaunchKernelGGL(convT_kernel, dim3(F_DIM / 64, D_DIM / 32, E_NUM), dim3(256), 0, stream,
                     W1, W1T, D_DIM, F_DIM);
  hipLaunchKernelGGL(convT_kernel, dim3(D_DIM / 64, F_DIM / 32, E_NUM), dim3(256), 0, stream,
                     W2, W2T, F_DIM, D_DIM);
  hipLaunchKernelGGL((moe_gemm_kernel<D_DIM, F_DIM, 1>), dim3(F_DIM / 128, T_TOK / 128, E_NUM), dim3(256), 0, stream,
                     h0p, W1T, b1, cnt, offs, H, nullptr);
  hipLaunchKernelGGL((moe_gemm_kernel<F_DIM, D_DIM, 2>), dim3(4 * 4, T_TOK / 128, E_NUM), dim3(256), 0, stream,
                     H, W2T, nullptr, cnt, offs, nullptr, Part);
  hipLaunchKernelGGL(reduce_kernel, dim3(T_TOK), dim3(128), 0, stream,
                     Part, x, b2, eid, alphav, posof, out);
}